// Round 11
// baseline (134.473 us; speedup 1.0000x reference)
//
#include <hip/hip_runtime.h>

// ---------------------------------------------------------------------------
// Convnet: 8 overlapping sections, conv [32x16] x 128 ch, threshold 15, pool
// (400,16), winner-take-all -> single channel index.
//
// R11: fp4 e2m1 everywhere (X scaled 2^6, W scaled 2^2, net 2^-8 applied via
//      the MFMA scale operands — only the product matters). Same 32x32x64
//      f8f6f4 instruction at fp4 format = 2x fp8 issue rate (m59), fragments
//      halve (A 2x b64, B 1x b128 per nt). W-in-LDS now 32 KB. K-loop back
//      to R9's proven unroll-2 (R10's full unroll spilled). Epilogue/winner
//      exactly R9 (winner micro-opt proved worthless: residual is harness
//      poison/launch overhead, not kernel time).
// ---------------------------------------------------------------------------

using int4v  = __attribute__((ext_vector_type(4))) int;
using int8v  = __attribute__((ext_vector_type(8))) int;
using f32x16 = __attribute__((ext_vector_type(16))) float;

#define THRESH 15.0f
#define SCALE_ONE 0x7F7F7F7F   // E8M0 127 = 2^0 per byte
#define SCALE_256 0x77777777   // E8M0 119 = 2^-8 per byte (net X*W scale)

// positive e2m1 code for v in [0, 6.5]: values {0,.5,1,1.5,2,3,4,6}
__device__ __forceinline__ unsigned f4enc(float v) {
  float r2 = __builtin_rintf(v + v);   // step .5 band (v<=2): codes 0..4
  float r1 = __builtin_rintf(v);       // step 1 band (2<v<=4): codes 4..6
  return (v <= 2.f) ? (unsigned)r2
       : (v <= 4.f) ? (unsigned)r1 + 2u
       : (v < 5.f)  ? 6u : 7u;
}

// ---------------- prep: W fp32 -> fp4 (x4 scale), per-section 32 KB layout:
//   addr = s*32768 + ch*4096 + ko*2048 + c*16   (ch = k64 chunk, ko = k32 half)
__global__ __launch_bounds__(256) void prep_kernel(const float* __restrict__ W,
                                                   unsigned char* __restrict__ Wp4,
                                                   int* __restrict__ pool) {
  int t = blockIdx.x * 256 + threadIdx.x;   // 64 blocks -> 16384 threads
  if (t < 15360) pool[t] = 0;
  int s = t >> 11, r = t & 2047, c = r >> 4, b = r & 15;   // b = k32 block
  const float* src = W + ((s * 128 + c) * 512 + b * 32);
  int4v o;
#pragma unroll
  for (int i = 0; i < 4; ++i) {
    unsigned d = 0;
#pragma unroll
    for (int e = 0; e < 8; ++e)
      d |= f4enc(fmaxf(src[i * 8 + e], 0.f) * 4.f) << (4 * e);
    o[i] = (int)d;
  }
  *(int4v*)(Wp4 + s * 32768 + (b >> 1) * 4096 + (b & 1) * 2048 + c * 16) = o;
}

// ---------------- conv + threshold + pool-OR
// grid: 8 s * 13 t-tiles(32) * 30 fo-tiles(8) = 3120 blocks, 256 threads
// block: M = 256 (32 t x 8 fo), N = 128 ch, K = 512 (k = kt*16+kf)
// wave w: fo offsets {2w, 2w+1}; mfma_scale_f32_32x32x64_f8f6f4 fp4/fp4:
//   lane holds 32 taps (16 B) of A and B; D col = lane&31. Nibble/dword tap
//   order identical on A and B -> any internal permutation cancels.
__global__ __launch_bounds__(256, 2) void conv_pool_kernel(const float* __restrict__ X,
                                                           const unsigned char* __restrict__ Wp4,
                                                           int* __restrict__ pool) {
  __shared__ __align__(16) unsigned char Ash[8 * 512];    // 4096 B: 8 fo copies, 63 rows x 8 B
  __shared__ __align__(16) unsigned char Bsh[32768];      // whole section's W, fp4
  __shared__ unsigned poolbits[32];

  const int tid = threadIdx.x;
  const int bid = blockIdx.x;
  const int s   = bid / 390;
  const int rem = bid % 390;
  const int tt  = rem / 30;
  const int ft  = rem % 30;
  const int t0  = (tt == 12) ? 368 : tt * 32;   // overlap recompute; OR idempotent
  const int fo0 = ft * 8, fp = ft >> 1;
  const int srow = s * 400 + t0;                // max 3168; +62 = 3230 in-bounds

  if (tid < 32) poolbits[tid] = 0;

  // ---- issue whole-W DMA: 2048 x 16 B, 8 per thread (drained by the barrier)
  {
    const unsigned char* wbase = Wp4 + s * 32768;
#pragma unroll
    for (int it = 0; it < 8; ++it) {
      int off = (it * 256 + tid) * 16;
      __builtin_amdgcn_global_load_lds(
          (const __attribute__((address_space(1))) void*)(wbase + off),
          (__attribute__((address_space(3))) void*)(&Bsh[off]), 16, 0, 0);
    }
  }

  // ---- stage A: 8 d x 63 rows, 16 taps -> 8 B fp4 per row (x64 scale)
  for (int i = tid; i < 504; i += 256) {
    int d = i / 63, r = i % 63;
    const float* xs = X + (srow + r) * 256 + fo0 + d;
    unsigned lo = 0, hi = 0;
#pragma unroll
    for (int e = 0; e < 8; ++e) {
      lo |= f4enc(xs[e] * 64.f) << (4 * e);
      hi |= f4enc(xs[e + 8] * 64.f) << (4 * e);
    }
    *(uint2*)&Ash[d * 512 + r * 8] = make_uint2(lo, hi);
  }

  f32x16 acc[2][4];
#pragma unroll
  for (int a = 0; a < 2; ++a)
#pragma unroll
    for (int b = 0; b < 4; ++b)
#pragma unroll
      for (int e = 0; e < 16; ++e) acc[a][b][e] = 0.f;

  const int w = tid >> 6, l = tid & 63;
  const int m31 = l & 31, ko = l >> 5;

  // per-lane LDS base offsets (bytes)
  const int abase0 = (2 * w) * 512 + (m31 + ko * 2) * 8;   // + ch*32 (+8 second row)
  const int abase1 = abase0 + 512;
  const int boff   = ko * 2048 + m31 * 16;                 // + ch*4096 + nt*512

  __syncthreads();   // W DMA + A copies + poolbits all ready; only barrier

  // ---- barrier-free K loop: 8 chunks of 64 taps, pure ds_read + MFMA
#pragma unroll 2
  for (int ch = 0; ch < 8; ++ch) {
    // A frags: rows (m31 + ko*2 + ch*4) and +1, 8 B each (taps j 0..15, 16..31)
    uint2 a0r0 = *(const uint2*)&Ash[abase0 + ch * 32];
    uint2 a0r1 = *(const uint2*)&Ash[abase0 + ch * 32 + 8];
    uint2 a1r0 = *(const uint2*)&Ash[abase1 + ch * 32];
    uint2 a1r1 = *(const uint2*)&Ash[abase1 + ch * 32 + 8];
    int8v A0 = {(int)a0r0.x, (int)a0r0.y, (int)a0r1.x, (int)a0r1.y, 0, 0, 0, 0};
    int8v A1 = {(int)a1r0.x, (int)a1r0.y, (int)a1r1.x, (int)a1r1.y, 0, 0, 0, 0};

    const unsigned char* bb = Bsh + ch * 4096 + boff;
#pragma unroll
    for (int nt = 0; nt < 4; ++nt) {
      int4v bq = *(const int4v*)(bb + nt * 512);   // ch n = nt*32+m31, 32 taps
      int8v Bf = {bq[0], bq[1], bq[2], bq[3], 0, 0, 0, 0};
      acc[0][nt] = __builtin_amdgcn_mfma_scale_f32_32x32x64_f8f6f4(
          A0, Bf, acc[0][nt], 4, 4, 0, SCALE_ONE, 0, SCALE_256);
      acc[1][nt] = __builtin_amdgcn_mfma_scale_f32_32x32x64_f8f6f4(
          A1, Bf, acc[1][nt], 4, 4, 0, SCALE_ONE, 0, SCALE_256);
    }
  }

  // ---- threshold + OR. Lane covers channels c = nt*32 + m31.
  unsigned sp = 0;
#pragma unroll
  for (int nt = 0; nt < 4; ++nt) {
    float m0 = -1e30f, m1 = -1e30f;
#pragma unroll
    for (int e = 0; e < 16; ++e) {
      m0 = fmaxf(m0, acc[0][nt][e]);
      m1 = fmaxf(m1, acc[1][nt][e]);
    }
    if (fmaxf(m0, m1) >= THRESH) sp |= (1u << nt);
  }
  sp |= __shfl_xor(sp, 32, 64);   // merge the two row-halves
  if (l < 32 && sp) atomicOr(&poolbits[m31], sp);
  __syncthreads();

  if (tid < 128) {
    unsigned bits = poolbits[tid & 31];
    if ((bits >> (tid >> 5)) & 1)
      pool[(s * 128 + tid) * 15 + fp] = 1;   // benign same-value race across blocks
  }
}

// ---------------- winner (reference get_k_winners semantics), pool in LDS
__global__ __launch_bounds__(256) void winner_kernel(const int* __restrict__ pool,
                                                     float* __restrict__ out) {
  __shared__ int lp[15360];
  __shared__ int sh_v;
  __shared__ int sh_best;
  int tid = threadIdx.x;
  if (tid == 0) { sh_v = 0; sh_best = 0; }
  for (int i = tid; i < 15360; i += 256) lp[i] = pool[i];
  __syncthreads();

  int localv = 0;
  for (int p = tid; p < 1920; p += 256) {
    int c = p / 15, f = p % 15;
    int cnt = 0;
    for (int s = 0; s < 8; ++s) cnt += lp[(s * 128 + c) * 15 + f];
    if (cnt > 0) {
      int early = 8 - cnt; if (early > 7) early = 7;
      localv |= lp[(early * 128 + c) * 15 + f];
    }
  }
  if (localv) atomicOr(&sh_v, 1);
  __syncthreads();

  const int v = sh_v * 8;   // trunc.max() * T
  int localbest = 0;
  for (int p = tid; p < 1920; p += 256) {
    int c = p / 15, f = p % 15;
    int cnt = 0;
    for (int s = 0; s < 8; ++s) cnt += lp[(s * 128 + c) * 15 + f];
    int early = 8 - cnt; if (early > 7) early = 7;
    int val = lp[(early * 128 + c) * 15 + f];
    int total = cnt * (val + v);
    int pack = (total << 12) | (4095 - p);   // max total, then smallest flat idx
    if (pack > localbest) localbest = pack;
  }
  atomicMax(&sh_best, localbest);
  __syncthreads();

  if (tid == 0) {
    int total = sh_best >> 12;
    int p = 4095 - (sh_best & 4095);
    int feat = p / 15;
    out[0] = (total != 0) ? (float)feat : -1.0f;
  }
}

// ---------------------------------------------------------------------------
extern "C" void kernel_launch(void* const* d_in, const int* in_sizes, int n_in,
                              void* d_out, int out_size, void* d_ws, size_t ws_size,
                              hipStream_t stream) {
  (void)in_sizes; (void)n_in; (void)out_size; (void)ws_size;
  const float* X = (const float*)d_in[0];
  const float* W = (const float*)d_in[1];
  unsigned char* Wp4 = (unsigned char*)d_ws;               // 262,144 B
  int* pool = (int*)((char*)d_ws + (1 << 18));             // 61,440 B

  prep_kernel<<<64, 256, 0, stream>>>(W, Wp4, pool);
  conv_pool_kernel<<<3120, 256, 0, stream>>>(X, Wp4, pool);
  winner_kernel<<<1, 256, 0, stream>>>(pool, (float*)d_out);
}

// Round 12
// 102.337 us; speedup vs baseline: 1.3140x; 1.3140x over previous
//
#include <hip/hip_runtime.h>

// ---------------------------------------------------------------------------
// Convnet: 8 overlapping sections, conv [32x16] x 128 ch, threshold 15, pool
// (400,16), winner-take-all -> single channel index.
//
// R12: R9 baseline (42 us conv, LDS-read-pipe bound: 96 b128/wave = 18.4K
//      cyc/round) with ONE change: B operand in fp4 (mixed MFMA cbsz=0 A-fp8,
//      blgp=4 B-fp4, B scale 2^-2). B reads halve -> 64 b128/wave = 12.3K
//      cyc/round. A path / staging / epilogue byte-identical to R9.
// ---------------------------------------------------------------------------

using int4v  = __attribute__((ext_vector_type(4))) int;
using int8v  = __attribute__((ext_vector_type(8))) int;
using f32x16 = __attribute__((ext_vector_type(16))) float;

#define THRESH 15.0f
#define SCALE_ONE 0x7F7F7F7F   // E8M0 127 = 2^0 per byte
#define SCALE_Q   0x7D7D7D7D   // E8M0 125 = 2^-2 per byte (undo W*4)

// positive e2m1 code for v in [0, 6.5]: values {0,.5,1,1.5,2,3,4,6}
__device__ __forceinline__ unsigned f4enc(float v) {
  float r2 = __builtin_rintf(v + v);   // step .5 band (v<=2): codes 0..4
  float r1 = __builtin_rintf(v);       // step 1 band (2<v<=4): codes 4..6
  return (v <= 2.f) ? (unsigned)r2
       : (v <= 4.f) ? (unsigned)r1 + 2u
       : (v < 5.f)  ? 6u : 7u;
}

// ---------------- prep: W fp32 -> fp4 e2m1 (x4 scale), per-section 32 KB:
//   addr = s*32768 + ch*4096 + ko*2048 + c*16   (ch = k64 chunk, ko = k32 half)
__global__ __launch_bounds__(256) void prep_kernel(const float* __restrict__ W,
                                                   unsigned char* __restrict__ Wp4,
                                                   int* __restrict__ pool) {
  int t = blockIdx.x * 256 + threadIdx.x;   // 64 blocks -> 16384 threads
  if (t < 15360) pool[t] = 0;
  int s = t >> 11, r = t & 2047, c = r >> 4, b = r & 15;   // b = k32 block
  const float* src = W + ((s * 128 + c) * 512 + b * 32);
  int4v o;
#pragma unroll
  for (int i = 0; i < 4; ++i) {
    unsigned d = 0;
#pragma unroll
    for (int e = 0; e < 8; ++e)
      d |= f4enc(fmaxf(src[i * 8 + e], 0.f) * 4.f) << (4 * e);
    o[i] = (int)d;
  }
  *(int4v*)(Wp4 + s * 32768 + (b >> 1) * 4096 + (b & 1) * 2048 + c * 16) = o;
}

// ---------------- conv + threshold + pool-OR
// grid: 8 s * 13 t-tiles(32) * 30 fo-tiles(8) = 3120 blocks, 256 threads
// block: M = 256 (32 t x 8 fo), N = 128 ch, K = 512 (k = kt*16+kf)
// wave w: fo offsets {2w, 2w+1}; mfma_scale_f32_32x32x64_f8f6f4 (A fp8, B fp4):
//   lane: A[m=lane&31][k=(lane>>5)*32+j] 32 B, B[k][n=lane&31] 16 B (4 regs),
//   D col = lane&31. Tap order identical on A and B -> permutation cancels.
__global__ __launch_bounds__(256, 2) void conv_pool_kernel(const float* __restrict__ X,
                                                           const unsigned char* __restrict__ Wp4,
                                                           int* __restrict__ pool) {
  __shared__ __align__(16) unsigned char Ash[8 * 1008];   // 8064 B, 8 fo-shifted copies (fp8)
  __shared__ __align__(16) unsigned char Bsh[32768];      // whole section's W, fp4
  __shared__ unsigned poolbits[32];

  const int tid = threadIdx.x;
  const int bid = blockIdx.x;
  const int s   = bid / 390;
  const int rem = bid % 390;
  const int tt  = rem / 30;
  const int ft  = rem % 30;
  const int t0  = (tt == 12) ? 368 : tt * 32;   // overlap recompute; OR idempotent
  const int fo0 = ft * 8, fp = ft >> 1;
  const int srow = s * 400 + t0;                // max 3168; +62 = 3230 in-bounds

  if (tid < 32) poolbits[tid] = 0;

  // ---- issue whole-W DMA: 2048 x 16 B, 8 per thread (drained by the barrier)
  {
    const unsigned char* wbase = Wp4 + s * 32768;
#pragma unroll
    for (int it = 0; it < 8; ++it) {
      int off = (it * 256 + tid) * 16;
      __builtin_amdgcn_global_load_lds(
          (const __attribute__((address_space(1))) void*)(wbase + off),
          (__attribute__((address_space(3))) void*)(&Bsh[off]), 16, 0, 0);
    }
  }

  // ---- stage A: 8 d x 63 rows x 16 fp8 (stride-16 writes, conflict-free)
  for (int i = tid; i < 504; i += 256) {
    int d = i / 63, r = i % 63;
    const float* xs = X + (srow + r) * 256 + fo0 + d;
    int4v pk;
#pragma unroll
    for (int h = 0; h < 4; ++h) {
      int q = 0;
      q = __builtin_amdgcn_cvt_pk_fp8_f32(xs[h * 4 + 0], xs[h * 4 + 1], q, false);
      q = __builtin_amdgcn_cvt_pk_fp8_f32(xs[h * 4 + 2], xs[h * 4 + 3], q, true);
      pk[h] = q;
    }
    *(int4v*)&Ash[d * 1008 + r * 16] = pk;
  }

  f32x16 acc[2][4];
#pragma unroll
  for (int a = 0; a < 2; ++a)
#pragma unroll
    for (int b = 0; b < 4; ++b)
#pragma unroll
      for (int e = 0; e < 16; ++e) acc[a][b][e] = 0.f;

  const int w = tid >> 6, l = tid & 63;
  const int m31 = l & 31, ko = l >> 5;

  // per-lane LDS base offsets (bytes)
  const int aoff0 = (2 * w) * 1008 + m31 * 16 + ko * 32;       // + ch*64 (+16 hi)
  const int aoff1 = (2 * w + 1) * 1008 + m31 * 16 + ko * 32;
  const int boff  = ko * 2048 + m31 * 16;                      // + ch*4096 + nt*512

  __syncthreads();   // W DMA + A copies + poolbits all ready; only barrier

  // ---- barrier-free K loop: 8 chunks of 64 taps, pure ds_read + MFMA
#pragma unroll 2
  for (int ch = 0; ch < 8; ++ch) {
    // A frags (fp8): rows kt = ch*4 + ko*2 + {0,1} (+m31 shift), 2x16 B contiguous
    int4v a0lo = *(const int4v*)&Ash[aoff0 + ch * 64];
    int4v a0hi = *(const int4v*)&Ash[aoff0 + ch * 64 + 16];
    int4v a1lo = *(const int4v*)&Ash[aoff1 + ch * 64];
    int4v a1hi = *(const int4v*)&Ash[aoff1 + ch * 64 + 16];
    int8v A0 = {a0lo[0], a0lo[1], a0lo[2], a0lo[3], a0hi[0], a0hi[1], a0hi[2], a0hi[3]};
    int8v A1 = {a1lo[0], a1lo[1], a1lo[2], a1lo[3], a1hi[0], a1hi[1], a1hi[2], a1hi[3]};

    const unsigned char* bb = Bsh + ch * 4096 + boff;
#pragma unroll
    for (int nt = 0; nt < 4; ++nt) {
      int4v bq = *(const int4v*)(bb + nt * 512);   // ch n = nt*32+m31, 32 taps fp4
      int8v Bf = {bq[0], bq[1], bq[2], bq[3], 0, 0, 0, 0};
      acc[0][nt] = __builtin_amdgcn_mfma_scale_f32_32x32x64_f8f6f4(
          A0, Bf, acc[0][nt], 0, 4, 0, SCALE_ONE, 0, SCALE_Q);
      acc[1][nt] = __builtin_amdgcn_mfma_scale_f32_32x32x64_f8f6f4(
          A1, Bf, acc[1][nt], 0, 4, 0, SCALE_ONE, 0, SCALE_Q);
    }
  }

  // ---- threshold + OR. Lane covers channels c = nt*32 + m31.
  unsigned sp = 0;
#pragma unroll
  for (int nt = 0; nt < 4; ++nt) {
    float m0 = -1e30f, m1 = -1e30f;
#pragma unroll
    for (int e = 0; e < 16; ++e) {
      m0 = fmaxf(m0, acc[0][nt][e]);
      m1 = fmaxf(m1, acc[1][nt][e]);
    }
    if (fmaxf(m0, m1) >= THRESH) sp |= (1u << nt);
  }
  sp |= __shfl_xor(sp, 32, 64);   // merge the two row-halves
  if (l < 32 && sp) atomicOr(&poolbits[m31], sp);
  __syncthreads();

  if (tid < 128) {
    unsigned bits = poolbits[tid & 31];
    if ((bits >> (tid >> 5)) & 1)
      pool[(s * 128 + tid) * 15 + fp] = 1;   // benign same-value race across blocks
  }
}

// ---------------- winner (reference get_k_winners semantics), pool in LDS
__global__ __launch_bounds__(256) void winner_kernel(const int* __restrict__ pool,
                                                     float* __restrict__ out) {
  __shared__ int lp[15360];
  __shared__ int sh_v;
  __shared__ int sh_best;
  int tid = threadIdx.x;
  if (tid == 0) { sh_v = 0; sh_best = 0; }
  for (int i = tid; i < 15360; i += 256) lp[i] = pool[i];
  __syncthreads();

  int localv = 0;
  for (int p = tid; p < 1920; p += 256) {
    int c = p / 15, f = p % 15;
    int cnt = 0;
    for (int s = 0; s < 8; ++s) cnt += lp[(s * 128 + c) * 15 + f];
    if (cnt > 0) {
      int early = 8 - cnt; if (early > 7) early = 7;
      localv |= lp[(early * 128 + c) * 15 + f];
    }
  }
  if (localv) atomicOr(&sh_v, 1);
  __syncthreads();

  const int v = sh_v * 8;   // trunc.max() * T
  int localbest = 0;
  for (int p = tid; p < 1920; p += 256) {
    int c = p / 15, f = p % 15;
    int cnt = 0;
    for (int s = 0; s < 8; ++s) cnt += lp[(s * 128 + c) * 15 + f];
    int early = 8 - cnt; if (early > 7) early = 7;
    int val = lp[(early * 128 + c) * 15 + f];
    int total = cnt * (val + v);
    int pack = (total << 12) | (4095 - p);   // max total, then smallest flat idx
    if (pack > localbest) localbest = pack;
  }
  atomicMax(&sh_best, localbest);
  __syncthreads();

  if (tid == 0) {
    int total = sh_best >> 12;
    int p = 4095 - (sh_best & 4095);
    int feat = p / 15;
    out[0] = (total != 0) ? (float)feat : -1.0f;
  }
}

// ---------------------------------------------------------------------------
extern "C" void kernel_launch(void* const* d_in, const int* in_sizes, int n_in,
                              void* d_out, int out_size, void* d_ws, size_t ws_size,
                              hipStream_t stream) {
  (void)in_sizes; (void)n_in; (void)out_size; (void)ws_size;
  const float* X = (const float*)d_in[0];
  const float* W = (const float*)d_in[1];
  unsigned char* Wp4 = (unsigned char*)d_ws;               // 262,144 B
  int* pool = (int*)((char*)d_ws + (1 << 18));             // 61,440 B

  prep_kernel<<<64, 256, 0, stream>>>(W, Wp4, pool);
  conv_pool_kernel<<<3120, 256, 0, stream>>>(X, Wp4, pool);
  winner_kernel<<<1, 256, 0, stream>>>(pool, (float*)d_out);
}

// Round 13
// 101.824 us; speedup vs baseline: 1.3206x; 1.0050x over previous
//
#include <hip/hip_runtime.h>

// ---------------------------------------------------------------------------
// Convnet: 8 overlapping sections, conv [32x16] x 128 ch, threshold 15, pool
// (400,16), winner-take-all -> single channel index.
//
// R13: break the 2-wave/SIMD convoy (R12: LDS 6.1K + MFMA 8.8K cyc/round run
//      SERIALIZED at ~15.7K wall). Channel-split blocks (N=64, grid 6240,
//      acc 64 AGPRs) + launch_bounds(256,3) -> 3 blocks/CU, 3 waves/SIMD.
//      Per-round: LDS 6.9K vs MFMA 6.6K balanced, 1.5x TLP to overlap them.
//      A fp8 / B fp4 mixed MFMA as R12. W packed per (s,chalf) 16 KB.
// ---------------------------------------------------------------------------

using int4v  = __attribute__((ext_vector_type(4))) int;
using int8v  = __attribute__((ext_vector_type(8))) int;
using f32x16 = __attribute__((ext_vector_type(16))) float;

#define THRESH 15.0f
#define SCALE_ONE 0x7F7F7F7F   // E8M0 127 = 2^0 per byte
#define SCALE_Q   0x7D7D7D7D   // E8M0 125 = 2^-2 per byte (undo W*4)

// positive e2m1 code for v in [0, 6.5]: values {0,.5,1,1.5,2,3,4,6}
__device__ __forceinline__ unsigned f4enc(float v) {
  float r2 = __builtin_rintf(v + v);   // step .5 band (v<=2): codes 0..4
  float r1 = __builtin_rintf(v);       // step 1 band (2<v<=4): codes 4..6
  return (v <= 2.f) ? (unsigned)r2
       : (v <= 4.f) ? (unsigned)r1 + 2u
       : (v < 5.f)  ? 6u : 7u;
}

// ---------------- prep: W fp32 -> fp4 e2m1 (x4 scale), per-(s,chalf) 16 KB:
//   addr = s*32768 + chalf*16384 + ch*2048 + ko*1024 + c6*16
__global__ __launch_bounds__(256) void prep_kernel(const float* __restrict__ W,
                                                   unsigned char* __restrict__ Wp4,
                                                   int* __restrict__ pool) {
  int t = blockIdx.x * 256 + threadIdx.x;   // 64 blocks -> 16384 threads
  if (t < 15360) pool[t] = 0;
  int s = t >> 11, r = t & 2047, c = r >> 4, b = r & 15;   // b = k32 block
  const float* src = W + ((s * 128 + c) * 512 + b * 32);
  int4v o;
#pragma unroll
  for (int i = 0; i < 4; ++i) {
    unsigned d = 0;
#pragma unroll
    for (int e = 0; e < 8; ++e)
      d |= f4enc(fmaxf(src[i * 8 + e], 0.f) * 4.f) << (4 * e);
    o[i] = (int)d;
  }
  *(int4v*)(Wp4 + s * 32768 + (c >> 6) * 16384 + (b >> 1) * 2048
            + (b & 1) * 1024 + (c & 63) * 16) = o;
}

// ---------------- conv + threshold + pool-OR
// grid: 8 s * 13 t-tiles(32) * 30 fo-tiles(8) * 2 chalf = 6240 blocks
// block: M = 256 (32 t x 8 fo), N = 64 ch, K = 512 (k = kt*16+kf)
// wave w: fo offsets {2w, 2w+1}; mfma_scale_f32_32x32x64_f8f6f4 (A fp8, B fp4):
//   lane: A[m=lane&31][k=(lane>>5)*32+j] 32 B, B[k][n=lane&31] 16 B (4 regs),
//   D col = lane&31. Tap order identical on A and B -> permutation cancels.
__global__ __launch_bounds__(256, 3) void conv_pool_kernel(const float* __restrict__ X,
                                                           const unsigned char* __restrict__ Wp4,
                                                           int* __restrict__ pool) {
  __shared__ __align__(16) unsigned char Ash[8 * 1008];   // 8064 B, 8 fo-shifted copies (fp8)
  __shared__ __align__(16) unsigned char Bsh[16384];      // half-section W, fp4
  __shared__ unsigned poolbits[32];

  const int tid = threadIdx.x;
  const int bid = blockIdx.x;
  const int s   = bid / 780;
  const int rem = bid % 780;
  const int tt  = rem / 60;
  const int r2  = rem % 60;
  const int ft  = r2 >> 1;
  const int chalf = r2 & 1;
  const int t0  = (tt == 12) ? 368 : tt * 32;   // overlap recompute; OR idempotent
  const int fo0 = ft * 8, fp = ft >> 1;
  const int srow = s * 400 + t0;                // max 3168; +62 = 3230 in-bounds

  if (tid < 32) poolbits[tid] = 0;

  // ---- issue half-section W DMA: 1024 x 16 B, 4 per thread
  {
    const unsigned char* wbase = Wp4 + s * 32768 + chalf * 16384;
#pragma unroll
    for (int it = 0; it < 4; ++it) {
      int off = (it * 256 + tid) * 16;
      __builtin_amdgcn_global_load_lds(
          (const __attribute__((address_space(1))) void*)(wbase + off),
          (__attribute__((address_space(3))) void*)(&Bsh[off]), 16, 0, 0);
    }
  }

  // ---- stage A: 8 d x 63 rows x 16 fp8 (stride-16 writes, conflict-free)
  for (int i = tid; i < 504; i += 256) {
    int d = i / 63, r = i % 63;
    const float* xs = X + (srow + r) * 256 + fo0 + d;
    int4v pk;
#pragma unroll
    for (int h = 0; h < 4; ++h) {
      int q = 0;
      q = __builtin_amdgcn_cvt_pk_fp8_f32(xs[h * 4 + 0], xs[h * 4 + 1], q, false);
      q = __builtin_amdgcn_cvt_pk_fp8_f32(xs[h * 4 + 2], xs[h * 4 + 3], q, true);
      pk[h] = q;
    }
    *(int4v*)&Ash[d * 1008 + r * 16] = pk;
  }

  f32x16 acc[2][2];
#pragma unroll
  for (int a = 0; a < 2; ++a)
#pragma unroll
    for (int b = 0; b < 2; ++b)
#pragma unroll
      for (int e = 0; e < 16; ++e) acc[a][b][e] = 0.f;

  const int w = tid >> 6, l = tid & 63;
  const int m31 = l & 31, ko = l >> 5;

  // per-lane LDS base offsets (bytes)
  const int aoff0 = (2 * w) * 1008 + m31 * 16 + ko * 32;       // + ch*64 (+16 hi)
  const int aoff1 = (2 * w + 1) * 1008 + m31 * 16 + ko * 32;
  const int boff  = ko * 1024 + m31 * 16;                      // + ch*2048 + nt*512

  __syncthreads();   // W DMA + A copies + poolbits all ready; only barrier

  // ---- barrier-free K loop: 8 chunks of 64 taps, pure ds_read + MFMA
#pragma unroll 2
  for (int ch = 0; ch < 8; ++ch) {
    // A frags (fp8): rows kt = ch*4 + ko*2 + {0,1} (+m31 shift), 2x16 B contiguous
    int4v a0lo = *(const int4v*)&Ash[aoff0 + ch * 64];
    int4v a0hi = *(const int4v*)&Ash[aoff0 + ch * 64 + 16];
    int4v a1lo = *(const int4v*)&Ash[aoff1 + ch * 64];
    int4v a1hi = *(const int4v*)&Ash[aoff1 + ch * 64 + 16];
    int8v A0 = {a0lo[0], a0lo[1], a0lo[2], a0lo[3], a0hi[0], a0hi[1], a0hi[2], a0hi[3]};
    int8v A1 = {a1lo[0], a1lo[1], a1lo[2], a1lo[3], a1hi[0], a1hi[1], a1hi[2], a1hi[3]};

    const unsigned char* bb = Bsh + ch * 2048 + boff;
#pragma unroll
    for (int nt = 0; nt < 2; ++nt) {
      int4v bq = *(const int4v*)(bb + nt * 512);   // ch n = chalf*64+nt*32+m31, fp4
      int8v Bf = {bq[0], bq[1], bq[2], bq[3], 0, 0, 0, 0};
      acc[0][nt] = __builtin_amdgcn_mfma_scale_f32_32x32x64_f8f6f4(
          A0, Bf, acc[0][nt], 0, 4, 0, SCALE_ONE, 0, SCALE_Q);
      acc[1][nt] = __builtin_amdgcn_mfma_scale_f32_32x32x64_f8f6f4(
          A1, Bf, acc[1][nt], 0, 4, 0, SCALE_ONE, 0, SCALE_Q);
    }
  }

  // ---- threshold + OR. Lane covers channels c_local = nt*32 + m31.
  unsigned sp = 0;
#pragma unroll
  for (int nt = 0; nt < 2; ++nt) {
    float m0 = -1e30f, m1 = -1e30f;
#pragma unroll
    for (int e = 0; e < 16; ++e) {
      m0 = fmaxf(m0, acc[0][nt][e]);
      m1 = fmaxf(m1, acc[1][nt][e]);
    }
    if (fmaxf(m0, m1) >= THRESH) sp |= (1u << nt);
  }
  sp |= __shfl_xor(sp, 32, 64);   // merge the two row-halves
  if (l < 32 && sp) atomicOr(&poolbits[m31], sp);
  __syncthreads();

  if (tid < 64) {
    unsigned bits = poolbits[tid & 31];
    if ((bits >> (tid >> 5)) & 1)
      pool[(s * 128 + chalf * 64 + tid) * 15 + fp] = 1;   // benign same-value race
  }
}

// ---------------- winner (reference get_k_winners semantics), pool in LDS
__global__ __launch_bounds__(256) void winner_kernel(const int* __restrict__ pool,
                                                     float* __restrict__ out) {
  __shared__ int lp[15360];
  __shared__ int sh_v;
  __shared__ int sh_best;
  int tid = threadIdx.x;
  if (tid == 0) { sh_v = 0; sh_best = 0; }
  for (int i = tid; i < 15360; i += 256) lp[i] = pool[i];
  __syncthreads();

  int localv = 0;
  for (int p = tid; p < 1920; p += 256) {
    int c = p / 15, f = p % 15;
    int cnt = 0;
    for (int s = 0; s < 8; ++s) cnt += lp[(s * 128 + c) * 15 + f];
    if (cnt > 0) {
      int early = 8 - cnt; if (early > 7) early = 7;
      localv |= lp[(early * 128 + c) * 15 + f];
    }
  }
  if (localv) atomicOr(&sh_v, 1);
  __syncthreads();

  const int v = sh_v * 8;   // trunc.max() * T
  int localbest = 0;
  for (int p = tid; p < 1920; p += 256) {
    int c = p / 15, f = p % 15;
    int cnt = 0;
    for (int s = 0; s < 8; ++s) cnt += lp[(s * 128 + c) * 15 + f];
    int early = 8 - cnt; if (early > 7) early = 7;
    int val = lp[(early * 128 + c) * 15 + f];
    int total = cnt * (val + v);
    int pack = (total << 12) | (4095 - p);   // max total, then smallest flat idx
    if (pack > localbest) localbest = pack;
  }
  atomicMax(&sh_best, localbest);
  __syncthreads();

  if (tid == 0) {
    int total = sh_best >> 12;
    int p = 4095 - (sh_best & 4095);
    int feat = p / 15;
    out[0] = (total != 0) ? (float)feat : -1.0f;
  }
}

// ---------------------------------------------------------------------------
extern "C" void kernel_launch(void* const* d_in, const int* in_sizes, int n_in,
                              void* d_out, int out_size, void* d_ws, size_t ws_size,
                              hipStream_t stream) {
  (void)in_sizes; (void)n_in; (void)out_size; (void)ws_size;
  const float* X = (const float*)d_in[0];
  const float* W = (const float*)d_in[1];
  unsigned char* Wp4 = (unsigned char*)d_ws;               // 262,144 B
  int* pool = (int*)((char*)d_ws + (1 << 18));             // 61,440 B

  prep_kernel<<<64, 256, 0, stream>>>(W, Wp4, pool);
  conv_pool_kernel<<<6240, 256, 0, stream>>>(X, Wp4, pool);
  winner_kernel<<<1, 256, 0, stream>>>(pool, (float*)d_out);
}

// Round 14
// 98.741 us; speedup vs baseline: 1.3619x; 1.0312x over previous
//
#include <hip/hip_runtime.h>

// ---------------------------------------------------------------------------
// Convnet: 8 overlapping sections, conv [32x16] x 128 ch, threshold 15, pool
// (400,16), winner-take-all -> single channel index.
//
// R14: R12 config (N=128/block, A fp8 x B fp4 mixed MFMA, 2 blocks/CU — the
//      lowest-LDS-traffic point) + explicit 2-buffer register pipeline in the
//      K loop: load chunk ch+1's frags before chunk ch's MFMAs. Breaks the
//      post-barrier read/MFMA convoy (R9/R12/R13 all ran at pipe SUM ~40us,
//      not MAX ~24us). Named-buffer WAR reuse bounds hoisting (no R10 spill).
// ---------------------------------------------------------------------------

using int4v  = __attribute__((ext_vector_type(4))) int;
using int8v  = __attribute__((ext_vector_type(8))) int;
using f32x16 = __attribute__((ext_vector_type(16))) float;

#define THRESH 15.0f
#define SCALE_ONE 0x7F7F7F7F   // E8M0 127 = 2^0 per byte
#define SCALE_Q   0x7D7D7D7D   // E8M0 125 = 2^-2 per byte (undo W*4)

// positive e2m1 code for v in [0, 6.5]: values {0,.5,1,1.5,2,3,4,6}
__device__ __forceinline__ unsigned f4enc(float v) {
  float r2 = __builtin_rintf(v + v);   // step .5 band (v<=2): codes 0..4
  float r1 = __builtin_rintf(v);       // step 1 band (2<v<=4): codes 4..6
  return (v <= 2.f) ? (unsigned)r2
       : (v <= 4.f) ? (unsigned)r1 + 2u
       : (v < 5.f)  ? 6u : 7u;
}

// ---------------- prep: W fp32 -> fp4 e2m1 (x4 scale), per-section 32 KB:
//   addr = s*32768 + ch*4096 + ko*2048 + c*16   (ch = k64 chunk, ko = k32 half)
__global__ __launch_bounds__(256) void prep_kernel(const float* __restrict__ W,
                                                   unsigned char* __restrict__ Wp4,
                                                   int* __restrict__ pool) {
  int t = blockIdx.x * 256 + threadIdx.x;   // 64 blocks -> 16384 threads
  if (t < 15360) pool[t] = 0;
  int s = t >> 11, r = t & 2047, c = r >> 4, b = r & 15;   // b = k32 block
  const float* src = W + ((s * 128 + c) * 512 + b * 32);
  int4v o;
#pragma unroll
  for (int i = 0; i < 4; ++i) {
    unsigned d = 0;
#pragma unroll
    for (int e = 0; e < 8; ++e)
      d |= f4enc(fmaxf(src[i * 8 + e], 0.f) * 4.f) << (4 * e);
    o[i] = (int)d;
  }
  *(int4v*)(Wp4 + s * 32768 + (b >> 1) * 4096 + (b & 1) * 2048 + c * 16) = o;
}

// ---------------- conv + threshold + pool-OR
// grid: 8 s * 13 t-tiles(32) * 30 fo-tiles(8) = 3120 blocks, 256 threads
// block: M = 256 (32 t x 8 fo), N = 128 ch, K = 512 (k = kt*16+kf)
// wave w: fo offsets {2w, 2w+1}; mfma_scale_f32_32x32x64_f8f6f4 (A fp8, B fp4)
__global__ __launch_bounds__(256, 2) void conv_pool_kernel(const float* __restrict__ X,
                                                           const unsigned char* __restrict__ Wp4,
                                                           int* __restrict__ pool) {
  __shared__ __align__(16) unsigned char Ash[8 * 1008];   // 8064 B, 8 fo-shifted copies (fp8)
  __shared__ __align__(16) unsigned char Bsh[32768];      // whole section's W, fp4
  __shared__ unsigned poolbits[32];

  const int tid = threadIdx.x;
  const int bid = blockIdx.x;
  const int s   = bid / 390;
  const int rem = bid % 390;
  const int tt  = rem / 30;
  const int ft  = rem % 30;
  const int t0  = (tt == 12) ? 368 : tt * 32;   // overlap recompute; OR idempotent
  const int fo0 = ft * 8, fp = ft >> 1;
  const int srow = s * 400 + t0;                // max 3168; +62 = 3230 in-bounds

  if (tid < 32) poolbits[tid] = 0;

  // ---- issue whole-W DMA: 2048 x 16 B, 8 per thread (drained by the barrier)
  {
    const unsigned char* wbase = Wp4 + s * 32768;
#pragma unroll
    for (int it = 0; it < 8; ++it) {
      int off = (it * 256 + tid) * 16;
      __builtin_amdgcn_global_load_lds(
          (const __attribute__((address_space(1))) void*)(wbase + off),
          (__attribute__((address_space(3))) void*)(&Bsh[off]), 16, 0, 0);
    }
  }

  // ---- stage A: 8 d x 63 rows x 16 fp8 (stride-16 writes, conflict-free)
  for (int i = tid; i < 504; i += 256) {
    int d = i / 63, r = i % 63;
    const float* xs = X + (srow + r) * 256 + fo0 + d;
    int4v pk;
#pragma unroll
    for (int h = 0; h < 4; ++h) {
      int q = 0;
      q = __builtin_amdgcn_cvt_pk_fp8_f32(xs[h * 4 + 0], xs[h * 4 + 1], q, false);
      q = __builtin_amdgcn_cvt_pk_fp8_f32(xs[h * 4 + 2], xs[h * 4 + 3], q, true);
      pk[h] = q;
    }
    *(int4v*)&Ash[d * 1008 + r * 16] = pk;
  }

  f32x16 acc[2][4];
#pragma unroll
  for (int a = 0; a < 2; ++a)
#pragma unroll
    for (int b = 0; b < 4; ++b)
#pragma unroll
      for (int e = 0; e < 16; ++e) acc[a][b][e] = 0.f;

  const int w = tid >> 6, l = tid & 63;
  const int m31 = l & 31, ko = l >> 5;

  // per-lane LDS base offsets (bytes)
  const int aoff0 = (2 * w) * 1008 + m31 * 16 + ko * 32;       // + ch*64 (+16 hi)
  const int aoff1 = (2 * w + 1) * 1008 + m31 * 16 + ko * 32;
  const int boff  = ko * 2048 + m31 * 16;                      // + ch*4096 + nt*512

  __syncthreads();   // W DMA + A copies + poolbits all ready; only barrier

// load chunk chh's fragments into named buffers (8 ds_read_b128)
#define LOAD_CHUNK(chh, A0v, A1v, Bv)                                          \
  {                                                                            \
    int4v _a0lo = *(const int4v*)&Ash[aoff0 + (chh) * 64];                     \
    int4v _a0hi = *(const int4v*)&Ash[aoff0 + (chh) * 64 + 16];                \
    int4v _a1lo = *(const int4v*)&Ash[aoff1 + (chh) * 64];                     \
    int4v _a1hi = *(const int4v*)&Ash[aoff1 + (chh) * 64 + 16];                \
    A0v = (int8v){_a0lo[0], _a0lo[1], _a0lo[2], _a0lo[3],                      \
                  _a0hi[0], _a0hi[1], _a0hi[2], _a0hi[3]};                     \
    A1v = (int8v){_a1lo[0], _a1lo[1], _a1lo[2], _a1lo[3],                      \
                  _a1hi[0], _a1hi[1], _a1hi[2], _a1hi[3]};                     \
    const unsigned char* _bb = Bsh + (chh) * 4096 + boff;                      \
    Bv[0] = *(const int4v*)(_bb);                                              \
    Bv[1] = *(const int4v*)(_bb + 512);                                        \
    Bv[2] = *(const int4v*)(_bb + 1024);                                       \
    Bv[3] = *(const int4v*)(_bb + 1536);                                       \
  }

// 8 MFMAs on a buffer set (A fp8 cbsz=0, B fp4 blgp=4, B scale 2^-2)
#define MFMA_CHUNK(A0v, A1v, Bv)                                               \
  {                                                                            \
    _Pragma("unroll")                                                          \
    for (int nt = 0; nt < 4; ++nt) {                                           \
      int8v Bf = {Bv[nt][0], Bv[nt][1], Bv[nt][2], Bv[nt][3], 0, 0, 0, 0};     \
      acc[0][nt] = __builtin_amdgcn_mfma_scale_f32_32x32x64_f8f6f4(            \
          A0v, Bf, acc[0][nt], 0, 4, 0, SCALE_ONE, 0, SCALE_Q);                \
      acc[1][nt] = __builtin_amdgcn_mfma_scale_f32_32x32x64_f8f6f4(            \
          A1v, Bf, acc[1][nt], 0, 4, 0, SCALE_ONE, 0, SCALE_Q);                \
    }                                                                          \
  }

  // ---- barrier-free, register-pipelined K loop (2 buffer sets, stride 2)
  {
    int8v A0a, A1a, A0b, A1b;
    int4v Ba[4], Bb[4];
    LOAD_CHUNK(0, A0a, A1a, Ba);
#pragma unroll 1
    for (int ch = 0; ch < 8; ch += 2) {
      LOAD_CHUNK(ch + 1, A0b, A1b, Bb);     // in flight during a-MFMAs
      MFMA_CHUNK(A0a, A1a, Ba);
      int chn = (ch + 2 < 8) ? ch + 2 : 7;  // tail: redundant reload, branch-free
      LOAD_CHUNK(chn, A0a, A1a, Ba);        // in flight during b-MFMAs
      MFMA_CHUNK(A0b, A1b, Bb);
    }
  }

  // ---- threshold + OR. Lane covers channels c = nt*32 + m31.
  unsigned sp = 0;
#pragma unroll
  for (int nt = 0; nt < 4; ++nt) {
    float m0 = -1e30f, m1 = -1e30f;
#pragma unroll
    for (int e = 0; e < 16; ++e) {
      m0 = fmaxf(m0, acc[0][nt][e]);
      m1 = fmaxf(m1, acc[1][nt][e]);
    }
    if (fmaxf(m0, m1) >= THRESH) sp |= (1u << nt);
  }
  sp |= __shfl_xor(sp, 32, 64);   // merge the two row-halves
  if (l < 32 && sp) atomicOr(&poolbits[m31], sp);
  __syncthreads();

  if (tid < 128) {
    unsigned bits = poolbits[tid & 31];
    if ((bits >> (tid >> 5)) & 1)
      pool[(s * 128 + tid) * 15 + fp] = 1;   // benign same-value race across blocks
  }
}

// ---------------- winner (reference get_k_winners semantics), pool in LDS
__global__ __launch_bounds__(256) void winner_kernel(const int* __restrict__ pool,
                                                     float* __restrict__ out) {
  __shared__ int lp[15360];
  __shared__ int sh_v;
  __shared__ int sh_best;
  int tid = threadIdx.x;
  if (tid == 0) { sh_v = 0; sh_best = 0; }
  for (int i = tid; i < 15360; i += 256) lp[i] = pool[i];
  __syncthreads();

  int localv = 0;
  for (int p = tid; p < 1920; p += 256) {
    int c = p / 15, f = p % 15;
    int cnt = 0;
    for (int s = 0; s < 8; ++s) cnt += lp[(s * 128 + c) * 15 + f];
    if (cnt > 0) {
      int early = 8 - cnt; if (early > 7) early = 7;
      localv |= lp[(early * 128 + c) * 15 + f];
    }
  }
  if (localv) atomicOr(&sh_v, 1);
  __syncthreads();

  const int v = sh_v * 8;   // trunc.max() * T
  int localbest = 0;
  for (int p = tid; p < 1920; p += 256) {
    int c = p / 15, f = p % 15;
    int cnt = 0;
    for (int s = 0; s < 8; ++s) cnt += lp[(s * 128 + c) * 15 + f];
    int early = 8 - cnt; if (early > 7) early = 7;
    int val = lp[(early * 128 + c) * 15 + f];
    int total = cnt * (val + v);
    int pack = (total << 12) | (4095 - p);   // max total, then smallest flat idx
    if (pack > localbest) localbest = pack;
  }
  atomicMax(&sh_best, localbest);
  __syncthreads();

  if (tid == 0) {
    int total = sh_best >> 12;
    int p = 4095 - (sh_best & 4095);
    int feat = p / 15;
    out[0] = (total != 0) ? (float)feat : -1.0f;
  }
}

// ---------------------------------------------------------------------------
extern "C" void kernel_launch(void* const* d_in, const int* in_sizes, int n_in,
                              void* d_out, int out_size, void* d_ws, size_t ws_size,
                              hipStream_t stream) {
  (void)in_sizes; (void)n_in; (void)out_size; (void)ws_size;
  const float* X = (const float*)d_in[0];
  const float* W = (const float*)d_in[1];
  unsigned char* Wp4 = (unsigned char*)d_ws;               // 262,144 B
  int* pool = (int*)((char*)d_ws + (1 << 18));             // 61,440 B

  prep_kernel<<<64, 256, 0, stream>>>(W, Wp4, pool);
  conv_pool_kernel<<<3120, 256, 0, stream>>>(X, Wp4, pool);
  winner_kernel<<<1, 256, 0, stream>>>(pool, (float*)d_out);
}